// Round 14
// baseline (70.116 us; speedup 1.0000x reference)
//
#include <hip/hip_runtime.h>

#define C   64
#define H   128
#define W   128
#define HW  (H * W)
#define NB  8

using bf16x8 = __attribute__((ext_vector_type(8))) short;
using f32x4  = __attribute__((ext_vector_type(4))) float;

__device__ __forceinline__ unsigned short f2bf(float f) {
    unsigned u = __float_as_uint(f);
    return (unsigned short)((u + 0x7fffu + ((u >> 16) & 1u)) >> 16);
}

// ---------------------------------------------------------------------------
// Prep: per-lane MFMA fragment tables (layouts unchanged since round 6).
//   w1f[((s*4+m)*64+lane)*8+j], w2f[(((cc*9+tap)*2+ks)*64+lane)*8+j],
//   b2f[((cc*9+tap)*64+lane)*4+r]
// ---------------------------------------------------------------------------
__global__ __launch_bounds__(256) void prep_weights(
    const float* __restrict__ w1, const float* __restrict__ w2,
    const float* __restrict__ b2,
    unsigned short* __restrict__ w1f, unsigned short* __restrict__ w2f,
    float* __restrict__ b2f)
{
    int i = blockIdx.x * 256 + threadIdx.x;   // 0..36863
    if (i < 36864) {
        {   // w1f
            int j = i & 7, lane = (i >> 3) & 63, m = (i >> 9) & 3, s = i >> 11;
            int l15 = lane & 15, lhi = lane >> 4;
            int co = m * 16 + l15;
            int kk = s * 32 + lhi * 8 + j;
            int tap = kk >> 6, k = kk & 63;
            w1f[i] = f2bf(w1[co * 576 + k * 9 + tap]);
        }
        {   // w2f
            int j = i & 7, lane = (i >> 3) & 63, ks = (i >> 9) & 1, t9 = i >> 10;
            int tap = t9 % 9, cc = t9 / 9;
            int cp = cc * 16 + (lane & 15);
            int k = ks * 32 + (lane >> 4) * 8 + j;
            w2f[i] = f2bf(w2[(cp * 9 + tap) * 64 + k]);
        }
    }
    if (i < 9216) {  // b2f
        int r = i & 3, lane = (i >> 2) & 63, t9 = i >> 8;
        int tap = t9 % 9, cc = t9 / 9;
        int cpp = cc * 16 + ((lane >> 4) << 2) + r;
        b2f[i] = b2[cpp * 9 + tap];
    }
}

// ---------------------------------------------------------------------------
// transpose_y: y NCHW f32 -> yT[n][pix][k] bf16 (LDS-tiled, XOR-swizzled)
// ---------------------------------------------------------------------------
__global__ __launch_bounds__(256) void transpose_y(
    const float* __restrict__ y, unsigned short* __restrict__ yT)
{
    __shared__ unsigned short tl[64 * 64];
    const int t = threadIdx.x, b = blockIdx.x;
    const int n = b & 7, tile = b >> 3;
    const int px0 = tile * 64;
    const int wv = t >> 6, l = t & 63;

    const float* src = y + (size_t)n * C * HW + px0 + l;
    #pragma unroll
    for (int i = 0; i < 8; ++i) {
        int ch = wv * 16 + i * 2;
        float v0 = src[(size_t)ch * HW];
        float v1 = src[(size_t)(ch + 1) * HW];
        unsigned pk = (unsigned)f2bf(v0) | ((unsigned)f2bf(v1) << 16);
        *(unsigned*)&tl[l * 64 + (ch ^ ((l & 7) << 3))] = pk;
    }
    __syncthreads();

    const int px = t >> 2, c0 = (t & 3) * 16;
    const int xr = (px & 7) << 3;
    uint4 w0 = *(const uint4*)&tl[px * 64 + (c0 ^ xr)];
    uint4 w1 = *(const uint4*)&tl[px * 64 + ((c0 + 8) ^ xr)];
    unsigned short* dst = yT + ((size_t)n * HW + px0 + px) * 64 + c0;
    *(uint4*)&dst[0] = w0;
    *(uint4*)&dst[8] = w1;
}

// ---------------------------------------------------------------------------
// fused_dc: block = 8 waves (512 thr) = TWO image rows; wave = (row, 32-px
// strip) x all 64 channels — per-wave work identical to r13 (no thin-wave
// duplication). Weight staging is shared by 2 rows: per-CU staging traffic
// halves, barriers per row halve. LDS = 32 KB h + 36.9 KB weights = 69.6 KB
// -> 2 blocks/CU -> 16 waves/CU (4/SIMD, ~2.6x r13's measured residency).
// Phase 1: w1f staged in two 36,864 B chunks (2304 uint4 each).
// Phase 2: w2f+b2f staged per cc (1152+576 uint4, fits in same region).
// h strip stays wave-private (same strip written & read, no extra barrier).
// ---------------------------------------------------------------------------
__global__ __launch_bounds__(512, 1) void fused_dc(
    const float* __restrict__ x,
    const unsigned short* __restrict__ yT,
    const unsigned short* __restrict__ w1f,
    const float* __restrict__ b1,
    const unsigned short* __restrict__ w2f,
    const float* __restrict__ b2f,
    float* __restrict__ out)
{
    __shared__ unsigned short h_lds[2 * 128 * 64];             // 32 KB
    __shared__ __align__(16) unsigned short w_lds[18432];      // 36,864 B

    const int t = threadIdx.x, b = blockIdx.x;
    const int n = b & 7;                       // image n -> XCD n (L2 reuse)
    const int wid = t >> 6, lane = t & 63;
    const int l15 = lane & 15, lhi = lane >> 4;
    const int rsel = wid >> 2;                 // which of the block's 2 rows
    const int qw = (wid & 3) << 5;             // wave's 32-px strip
    const int p = (b >> 3) * 2 + rsel;         // this wave's image row

    const unsigned short* yTn = yT + (size_t)n * HW * 64;
    unsigned short* h_row = &h_lds[rsel * 128 * 64];

    // ---------------- phase 1: h row via implicit GEMM ----------------
    f32x4 acc[4][2];
    #pragma unroll
    for (int m = 0; m < 4; ++m)
        #pragma unroll
        for (int pt = 0; pt < 2; ++pt)
            acc[m][pt] = f32x4{0.f, 0.f, 0.f, 0.f};

    #pragma unroll
    for (int half = 0; half < 2; ++half) {
        if (half) __syncthreads();             // chunk-0 readers done
        {   // stage w1f half-chunk: 36,864 B = 2304 uint4, 512 threads
            const uint4* src = (const uint4*)w1f + half * 2304;
            uint4* dst = (uint4*)w_lds;
            #pragma unroll
            for (int j = 0; j < 4; ++j) dst[t + 512 * j] = src[t + 512 * j];
            if (t < 256) dst[t + 2048] = src[t + 2048];
        }
        __syncthreads();

        #pragma unroll
        for (int sp = 0; sp < 9; ++sp) {
            const int s = half * 9 + sp;
            const int tap = s >> 1, trow = tap / 3, dq = tap % 3 - 1;
            const int k0 = (s & 1) * 32 + lhi * 8;
            const int grow = p + trow - 1;
            const bool rok = (unsigned)grow < (unsigned)H;
            const int cg = rok ? grow : 0;

            bf16x8 Y[2];
            #pragma unroll
            for (int pt = 0; pt < 2; ++pt) {
                int col = qw + pt * 16 + l15 + dq;
                bool ok = rok && ((unsigned)col < (unsigned)W);
                int cl = col < 0 ? 0 : (col > 127 ? 127 : col);
                bf16x8 v = *(const bf16x8*)&yTn[((size_t)cg * W + cl) * 64 + k0];
                Y[pt] = ok ? v : (bf16x8)0;
            }
            bf16x8 Wf[4];
            #pragma unroll
            for (int m = 0; m < 4; ++m)
                Wf[m] = *(const bf16x8*)&w_lds[((sp * 4 + m) * 64 + lane) * 8];

            #pragma unroll
            for (int m = 0; m < 4; ++m)
                #pragma unroll
                for (int pt = 0; pt < 2; ++pt)
                    acc[m][pt] = __builtin_amdgcn_mfma_f32_16x16x32_bf16(
                        Wf[m], Y[pt], acc[m][pt], 0, 0, 0);
        }
    }

    // +b1, pack bf16, swizzled write into this wave's strip of its h row
    #pragma unroll
    for (int m = 0; m < 4; ++m) {
        float4 bq1 = *(const float4*)&b1[m * 16 + lhi * 4];
        #pragma unroll
        for (int pt = 0; pt < 2; ++pt) {
            int px = qw + pt * 16 + l15;
            int cb = m * 16 + lhi * 4;
            unsigned lo = (unsigned)f2bf(acc[m][pt][0] + bq1.x)
                        | ((unsigned)f2bf(acc[m][pt][1] + bq1.y) << 16);
            unsigned hi = (unsigned)f2bf(acc[m][pt][2] + bq1.z)
                        | ((unsigned)f2bf(acc[m][pt][3] + bq1.w) << 16);
            uint2 pk; pk.x = lo; pk.y = hi;
            *(uint2*)&h_row[px * 64 + (cb ^ ((px & 7) << 3))] = pk;
        }
    }

    // hA readback: wave-private strip, no barrier needed
    bf16x8 hA[2][2];   // B-frags: lane l15 = pixel, k = lhi*8
    #pragma unroll
    for (int pt = 0; pt < 2; ++pt)
        #pragma unroll
        for (int ks = 0; ks < 2; ++ks) {
            int px = qw + pt * 16 + l15;
            int ko = ks * 32 + lhi * 8;
            hA[pt][ks] = *(const bf16x8*)&h_row[px * 64 + (ko ^ ((px & 7) << 3))];
        }

    // ---------------- phase 2: dynamic conv, w2 staged per cc ----------
    const float* xn_ = x + (size_t)n * C * HW;
    float* out_ = out + (size_t)n * C * HW;

    #pragma unroll
    for (int cc = 0; cc < 4; ++cc) {
        __syncthreads();                       // previous W-region readers done
        {   // stage w2f slice (1152 uint4) + b2f slice (576 uint4), 512 thr
            const uint4* src = (const uint4*)(w2f + cc * 9216);
            uint4* dst = (uint4*)w_lds;
            #pragma unroll
            for (int j = 0; j < 2; ++j) dst[t + 512 * j] = src[t + 512 * j];
            if (t < 128) dst[t + 1024] = src[t + 1024];
            const uint4* srcb = (const uint4*)(b2f + cc * 2304);
            uint4* dstb = (uint4*)(w_lds + 9216);
            dstb[t] = srcb[t < 576 ? t : 0];
            if (t < 64) dstb[t + 512] = srcb[t + 512];
        }
        __syncthreads();

        const float* b2l = (const float*)(w_lds + 9216);

        bf16x8 wA0[2], wA1[2];
        f32x4  bq[2];
        float  xv[2][2][4];   // [buf][pt][r]

        auto loadTap = [&](int tap, int bi) {
            wA0[bi] = *(const bf16x8*)&w_lds[((tap * 2 + 0) * 64 + lane) * 8];
            wA1[bi] = *(const bf16x8*)&w_lds[((tap * 2 + 1) * 64 + lane) * 8];
            bq[bi]  = *(const f32x4*)&b2l[(tap * 64 + lane) * 4];
            const int ri = tap / 3, cj = tap % 3;
            const int grow = p + ri - 1;                    // wave-uniform
            const bool rok = (unsigned)grow < (unsigned)H;
            const int cr = rok ? grow : 0;
            #pragma unroll
            for (int pt = 0; pt < 2; ++pt) {
                int col = qw + pt * 16 + l15 + cj - 1;
                bool ok = rok && ((unsigned)col < (unsigned)W);
                int cl = col < 0 ? 0 : (col > 127 ? 127 : col);
                const float* xb = xn_ + (size_t)(cc * 16 + lhi * 4) * HW
                                + (size_t)cr * W + cl;
                #pragma unroll
                for (int r = 0; r < 4; ++r) {
                    float v = xb[(size_t)r * HW];
                    xv[bi][pt][r] = ok ? v : 0.f;
                }
            }
        };

        f32x4 oacc[2];
        oacc[0] = f32x4{0.f, 0.f, 0.f, 0.f};
        oacc[1] = f32x4{0.f, 0.f, 0.f, 0.f};

        loadTap(0, 0);
        #pragma unroll
        for (int tap = 0; tap < 9; ++tap) {
            if (tap < 8) loadTap(tap + 1, (tap + 1) & 1);
            const int bi = tap & 1;
            #pragma unroll
            for (int pt = 0; pt < 2; ++pt) {
                f32x4 kf = __builtin_amdgcn_mfma_f32_16x16x32_bf16(
                    wA0[bi], hA[pt][0], bq[bi], 0, 0, 0);
                kf = __builtin_amdgcn_mfma_f32_16x16x32_bf16(
                    wA1[bi], hA[pt][1], kf, 0, 0, 0);
                #pragma unroll
                for (int r = 0; r < 4; ++r)
                    oacc[pt][r] = fmaf(kf[r], xv[bi][pt][r], oacc[pt][r]);
            }
        }

        // coalesced stores: lane l15 = consecutive pixels
        #pragma unroll
        for (int pt = 0; pt < 2; ++pt)
            #pragma unroll
            for (int r = 0; r < 4; ++r)
                out_[(size_t)(cc * 16 + lhi * 4 + r) * HW
                     + (size_t)p * W + qw + pt * 16 + l15] = oacc[pt][r];
    }
}

extern "C" void kernel_launch(void* const* d_in, const int* in_sizes, int n_in,
                              void* d_out, int out_size, void* d_ws, size_t ws_size,
                              hipStream_t stream)
{
    const float* x  = (const float*)d_in[0];
    const float* y  = (const float*)d_in[1];
    const float* w1 = (const float*)d_in[2];
    const float* b1 = (const float*)d_in[3];
    const float* w2 = (const float*)d_in[4];
    const float* b2 = (const float*)d_in[5];
    float* out = (float*)d_out;

    char* ws = (char*)d_ws;
    unsigned short* yT  = (unsigned short*)ws;                        // 16,777,216 B
    unsigned short* w1f = (unsigned short*)(ws + 16777216);           // 73,728 B
    unsigned short* w2f = (unsigned short*)(ws + 16777216 + 73728);   // 73,728 B
    float*          b2f = (float*)(ws + 16777216 + 147456);           // 36,864 B

    prep_weights<<<144, 256, 0, stream>>>(w1, w2, b2, w1f, w2f, b2f);
    transpose_y<<<NB * HW / 64, 256, 0, stream>>>(y, yT);
    fused_dc<<<NB * H / 2, 512, 0, stream>>>(x, yT, w1f, b1, w2f, b2f, out);
}

// Round 15
// 66.571 us; speedup vs baseline: 1.0533x; 1.0533x over previous
//
#include <hip/hip_runtime.h>

#define C   64
#define H   128
#define W   128
#define HW  (H * W)
#define NB  8

using bf16x8 = __attribute__((ext_vector_type(8))) short;
using f32x4  = __attribute__((ext_vector_type(4))) float;

__device__ __forceinline__ unsigned short f2bf(float f) {
    unsigned u = __float_as_uint(f);
    return (unsigned short)((u + 0x7fffu + ((u >> 16) & 1u)) >> 16);
}

// async global->LDS, 16B per lane (dest = wave-uniform base + lane*16)
__device__ __forceinline__ void gl_lds16(const void* g, void* l) {
    __builtin_amdgcn_global_load_lds(
        (const __attribute__((address_space(1))) unsigned int*)g,
        (__attribute__((address_space(3))) unsigned int*)l,
        16, 0, 0);
}

// ---------------------------------------------------------------------------
// Prep: per-lane MFMA fragment tables (layouts unchanged since round 6).
//   w1f[((s*4+m)*64+lane)*8+j], w2f[(((cc*9+tap)*2+ks)*64+lane)*8+j],
//   b2f[((cc*9+tap)*64+lane)*4+r]
// ---------------------------------------------------------------------------
__global__ __launch_bounds__(256) void prep_weights(
    const float* __restrict__ w1, const float* __restrict__ w2,
    const float* __restrict__ b2,
    unsigned short* __restrict__ w1f, unsigned short* __restrict__ w2f,
    float* __restrict__ b2f)
{
    int i = blockIdx.x * 256 + threadIdx.x;   // 0..36863
    if (i < 36864) {
        {   // w1f
            int j = i & 7, lane = (i >> 3) & 63, m = (i >> 9) & 3, s = i >> 11;
            int l15 = lane & 15, lhi = lane >> 4;
            int co = m * 16 + l15;
            int kk = s * 32 + lhi * 8 + j;
            int tap = kk >> 6, k = kk & 63;
            w1f[i] = f2bf(w1[co * 576 + k * 9 + tap]);
        }
        {   // w2f
            int j = i & 7, lane = (i >> 3) & 63, ks = (i >> 9) & 1, t9 = i >> 10;
            int tap = t9 % 9, cc = t9 / 9;
            int cp = cc * 16 + (lane & 15);
            int k = ks * 32 + (lane >> 4) * 8 + j;
            w2f[i] = f2bf(w2[(cp * 9 + tap) * 64 + k]);
        }
    }
    if (i < 9216) {  // b2f
        int r = i & 3, lane = (i >> 2) & 63, t9 = i >> 8;
        int tap = t9 % 9, cc = t9 / 9;
        int cpp = cc * 16 + ((lane >> 4) << 2) + r;
        b2f[i] = b2[cpp * 9 + tap];
    }
}

// ---------------------------------------------------------------------------
// transpose_y: y NCHW f32 -> yT[n][pix][k] bf16 (LDS-tiled, XOR-swizzled)
// ---------------------------------------------------------------------------
__global__ __launch_bounds__(256) void transpose_y(
    const float* __restrict__ y, unsigned short* __restrict__ yT)
{
    __shared__ unsigned short tl[64 * 64];
    const int t = threadIdx.x, b = blockIdx.x;
    const int n = b & 7, tile = b >> 3;
    const int px0 = tile * 64;
    const int wv = t >> 6, l = t & 63;

    const float* src = y + (size_t)n * C * HW + px0 + l;
    #pragma unroll
    for (int i = 0; i < 8; ++i) {
        int ch = wv * 16 + i * 2;
        float v0 = src[(size_t)ch * HW];
        float v1 = src[(size_t)(ch + 1) * HW];
        unsigned pk = (unsigned)f2bf(v0) | ((unsigned)f2bf(v1) << 16);
        *(unsigned*)&tl[l * 64 + (ch ^ ((l & 7) << 3))] = pk;
    }
    __syncthreads();

    const int px = t >> 2, c0 = (t & 3) * 16;
    const int xr = (px & 7) << 3;
    uint4 w0 = *(const uint4*)&tl[px * 64 + (c0 ^ xr)];
    uint4 w1 = *(const uint4*)&tl[px * 64 + ((c0 + 8) ^ xr)];
    unsigned short* dst = yT + ((size_t)n * HW + px0 + px) * 64 + c0;
    *(uint4*)&dst[0] = w0;
    *(uint4*)&dst[8] = w1;
}

// ---------------------------------------------------------------------------
// fused_dc: block = 4 waves = ONE image row (r13 geometry), with the §5.5
// T3-lite async pipeline: weight chunks staged via global_load_lds into a
// 2x18.4 KB double buffer, ISSUED one chunk ahead of use, one barrier per
// chunk (never a cold vmcnt drain except the single prologue barrier).
// Phase 1: 6 chunks x 3 stages (12.3 KB) of w1f.  Phase 2: 4 per-cc slices
// (18.4 KB) of w2f; b2 bias read direct from global (16 B/lane coalesced).
// LDS = 16 KB h + 36.9 KB weights = 53 KB -> 3 blocks/CU.
// ---------------------------------------------------------------------------
__global__ __launch_bounds__(256, 1) void fused_dc(
    const float* __restrict__ x,
    const unsigned short* __restrict__ yT,
    const unsigned short* __restrict__ w1f,
    const float* __restrict__ b1,
    const unsigned short* __restrict__ w2f,
    const float* __restrict__ b2f,
    float* __restrict__ out)
{
    __shared__ unsigned short h_lds[128 * 64];                 // 16,384 B
    __shared__ __align__(16) unsigned short w_lds[2][9216];    // 2 x 18,432 B

    const int t = threadIdx.x, b = blockIdx.x;
    const int n = b & 7;                       // image n -> XCD n (L2 reuse)
    const int p = b >> 3;                      // this block's image row
    const int wid = t >> 6, lane = t & 63;
    const int l15 = lane & 15, lhi = lane >> 4;
    const int qw = wid << 5;                   // wave's 32-px strip

    const unsigned short* yTn = yT + (size_t)n * HW * 64;

    // ---- async staging helpers (issue-only; barrier drains) ----
    auto stage_p1 = [&](int q, int buf) {      // 12,288 B chunk of w1f
        const char* src = (const char*)w1f + q * 12288 + t * 16;
        char* dstb = (char*)&w_lds[buf][0] + wid * 1024;
        #pragma unroll
        for (int j = 0; j < 3; ++j)
            gl_lds16(src + j * 4096, dstb + j * 4096);
    };
    auto stage_p2 = [&](int cc, int buf) {     // 18,432 B slice of w2f
        const char* src = (const char*)w2f + cc * 18432 + t * 16;
        char* dstb = (char*)&w_lds[buf][0] + wid * 1024;
        #pragma unroll
        for (int j = 0; j < 4; ++j)
            gl_lds16(src + j * 4096, dstb + j * 4096);
        if (wid < 2)
            gl_lds16(src + 4 * 4096, dstb + 4 * 4096);
    };

    // ---------------- phase 1: h row via implicit GEMM ----------------
    stage_p1(0, 0);                            // prologue (only cold drain)

    f32x4 acc[4][2];
    #pragma unroll
    for (int m = 0; m < 4; ++m)
        #pragma unroll
        for (int pt = 0; pt < 2; ++pt)
            acc[m][pt] = f32x4{0.f, 0.f, 0.f, 0.f};

    __syncthreads();

    #pragma unroll
    for (int q = 0; q < 6; ++q) {
        // issue next chunk's staging BEFORE this chunk's compute
        if (q < 5) stage_p1(q + 1, (q + 1) & 1);
        else       stage_p2(0, 0);             // pre-stage first w2 slice

        const unsigned short* wb = &w_lds[q & 1][0];
        #pragma unroll
        for (int sp = 0; sp < 3; ++sp) {
            const int s = q * 3 + sp;
            const int tap = s >> 1, trow = tap / 3, dq = tap % 3 - 1;
            const int k0 = (s & 1) * 32 + lhi * 8;
            const int grow = p + trow - 1;
            const bool rok = (unsigned)grow < (unsigned)H;
            const int cg = rok ? grow : 0;

            bf16x8 Y[2];
            #pragma unroll
            for (int pt = 0; pt < 2; ++pt) {
                int col = qw + pt * 16 + l15 + dq;
                bool ok = rok && ((unsigned)col < (unsigned)W);
                int cl = col < 0 ? 0 : (col > 127 ? 127 : col);
                bf16x8 v = *(const bf16x8*)&yTn[((size_t)cg * W + cl) * 64 + k0];
                Y[pt] = ok ? v : (bf16x8)0;
            }
            bf16x8 Wf[4];
            #pragma unroll
            for (int m = 0; m < 4; ++m)
                Wf[m] = *(const bf16x8*)&wb[((sp * 4 + m) * 64 + lane) * 8];

            #pragma unroll
            for (int m = 0; m < 4; ++m)
                #pragma unroll
                for (int pt = 0; pt < 2; ++pt)
                    acc[m][pt] = __builtin_amdgcn_mfma_f32_16x16x32_bf16(
                        Wf[m], Y[pt], acc[m][pt], 0, 0, 0);
        }
        __syncthreads();   // next chunk staged; this chunk's buffer now free
    }

    // +b1, pack bf16, swizzled write into this wave's strip (wave-private)
    #pragma unroll
    for (int m = 0; m < 4; ++m) {
        float4 bq1 = *(const float4*)&b1[m * 16 + lhi * 4];
        #pragma unroll
        for (int pt = 0; pt < 2; ++pt) {
            int px = qw + pt * 16 + l15;
            int cb = m * 16 + lhi * 4;
            unsigned lo = (unsigned)f2bf(acc[m][pt][0] + bq1.x)
                        | ((unsigned)f2bf(acc[m][pt][1] + bq1.y) << 16);
            unsigned hi = (unsigned)f2bf(acc[m][pt][2] + bq1.z)
                        | ((unsigned)f2bf(acc[m][pt][3] + bq1.w) << 16);
            uint2 pk; pk.x = lo; pk.y = hi;
            *(uint2*)&h_lds[px * 64 + (cb ^ ((px & 7) << 3))] = pk;
        }
    }

    // hA readback: same wave's strip (lgkmcnt-ordered, no barrier)
    bf16x8 hA[2][2];
    #pragma unroll
    for (int pt = 0; pt < 2; ++pt)
        #pragma unroll
        for (int ks = 0; ks < 2; ++ks) {
            int px = qw + pt * 16 + l15;
            int ko = ks * 32 + lhi * 8;
            hA[pt][ks] = *(const bf16x8*)&h_lds[px * 64 + (ko ^ ((px & 7) << 3))];
        }

    // ---------------- phase 2: dynamic conv ----------------
    const float* xn_ = x + (size_t)n * C * HW;
    float* out_ = out + (size_t)n * C * HW;

    #pragma unroll
    for (int cc = 0; cc < 4; ++cc) {
        if (cc == 0) __syncthreads();          // drains pre-staged slice 0
        if (cc < 3) stage_p2(cc + 1, (cc + 1) & 1);   // issue next slice

        const unsigned short* wb = &w_lds[cc & 1][0];

        bf16x8 wA0[2], wA1[2];
        f32x4  bq[2];
        float  xv[2][2][4];   // [buf][pt][r]

        auto loadTap = [&](int tap, int bi) {
            wA0[bi] = *(const bf16x8*)&wb[((tap * 2 + 0) * 64 + lane) * 8];
            wA1[bi] = *(const bf16x8*)&wb[((tap * 2 + 1) * 64 + lane) * 8];
            bq[bi]  = *(const f32x4*)&b2f[(size_t)((cc * 9 + tap) * 64 + lane) * 4];
            const int ri = tap / 3, cj = tap % 3;
            const int grow = p + ri - 1;                    // wave-uniform
            const bool rok = (unsigned)grow < (unsigned)H;
            const int cr = rok ? grow : 0;
            #pragma unroll
            for (int pt = 0; pt < 2; ++pt) {
                int col = qw + pt * 16 + l15 + cj - 1;
                bool ok = rok && ((unsigned)col < (unsigned)W);
                int cl = col < 0 ? 0 : (col > 127 ? 127 : col);
                const float* xb = xn_ + (size_t)(cc * 16 + lhi * 4) * HW
                                + (size_t)cr * W + cl;
                #pragma unroll
                for (int r = 0; r < 4; ++r) {
                    float v = xb[(size_t)r * HW];
                    xv[bi][pt][r] = ok ? v : 0.f;
                }
            }
        };

        f32x4 oacc[2];
        oacc[0] = f32x4{0.f, 0.f, 0.f, 0.f};
        oacc[1] = f32x4{0.f, 0.f, 0.f, 0.f};

        loadTap(0, 0);
        #pragma unroll
        for (int tap = 0; tap < 9; ++tap) {
            if (tap < 8) loadTap(tap + 1, (tap + 1) & 1);
            const int bi = tap & 1;
            #pragma unroll
            for (int pt = 0; pt < 2; ++pt) {
                f32x4 kf = __builtin_amdgcn_mfma_f32_16x16x32_bf16(
                    wA0[bi], hA[pt][0], bq[bi], 0, 0, 0);
                kf = __builtin_amdgcn_mfma_f32_16x16x32_bf16(
                    wA1[bi], hA[pt][1], kf, 0, 0, 0);
                #pragma unroll
                for (int r = 0; r < 4; ++r)
                    oacc[pt][r] = fmaf(kf[r], xv[bi][pt][r], oacc[pt][r]);
            }
        }

        // coalesced stores: lane l15 = consecutive pixels
        #pragma unroll
        for (int pt = 0; pt < 2; ++pt)
            #pragma unroll
            for (int r = 0; r < 4; ++r)
                out_[(size_t)(cc * 16 + lhi * 4 + r) * HW
                     + (size_t)p * W + qw + pt * 16 + l15] = oacc[pt][r];

        if (cc < 3) __syncthreads();           // next slice staged & buffer free
    }
}

extern "C" void kernel_launch(void* const* d_in, const int* in_sizes, int n_in,
                              void* d_out, int out_size, void* d_ws, size_t ws_size,
                              hipStream_t stream)
{
    const float* x  = (const float*)d_in[0];
    const float* y  = (const float*)d_in[1];
    const float* w1 = (const float*)d_in[2];
    const float* b1 = (const float*)d_in[3];
    const float* w2 = (const float*)d_in[4];
    const float* b2 = (const float*)d_in[5];
    float* out = (float*)d_out;

    char* ws = (char*)d_ws;
    unsigned short* yT  = (unsigned short*)ws;                        // 16,777,216 B
    unsigned short* w1f = (unsigned short*)(ws + 16777216);           // 73,728 B
    unsigned short* w2f = (unsigned short*)(ws + 16777216 + 73728);   // 73,728 B
    float*          b2f = (float*)(ws + 16777216 + 147456);           // 36,864 B

    prep_weights<<<144, 256, 0, stream>>>(w1, w2, b2, w1f, w2f, b2f);
    transpose_y<<<NB * HW / 64, 256, 0, stream>>>(y, yT);
    fused_dc<<<NB * H, 256, 0, stream>>>(x, yT, w1f, b1, w2f, b2f, out);
}